// Round 5
// baseline (850.498 us; speedup 1.0000x reference)
//
#include <hip/hip_runtime.h>
#include <hip/hip_bf16.h>
#include <math.h>

#define NB 8
#define LSEQ 5000
#define DIN 12
#define HCH 256
#define N2C 32
#define NLAY 6
#define G2C 512
#define TTC 64
#define NCH 79
#define LPAD 5120

typedef __attribute__((ext_vector_type(8))) short bf8v;
typedef __attribute__((ext_vector_type(8))) unsigned short us8v;
typedef __attribute__((ext_vector_type(4))) float f32x4;

#define MFMA16(a,b,c) __builtin_amdgcn_mfma_f32_16x16x32_bf16((a),(b),(c),0,0,0)

static __device__ __forceinline__ unsigned short f2bf(float f){
  unsigned int u = __float_as_uint(f);
  u = u + 0x7FFFu + ((u >> 16) & 1u);
  return (unsigned short)(u >> 16);
}
static __device__ __forceinline__ float bf2f(unsigned short s){
  return __uint_as_float(((unsigned int)s) << 16);
}
static __device__ __forceinline__ bf8v pack8(float4 a, float4 b){
  bf8v r;
  r[0]=(short)f2bf(a.x); r[1]=(short)f2bf(a.y); r[2]=(short)f2bf(a.z); r[3]=(short)f2bf(a.w);
  r[4]=(short)f2bf(b.x); r[5]=(short)f2bf(b.y); r[6]=(short)f2bf(b.z); r[7]=(short)f2bf(b.w);
  return r;
}
static __device__ __forceinline__ float gelu_f(float x){
  return 0.5f*x*(1.0f + erff(x*0.70710678118654752f));
}
static __device__ __forceinline__ float sigm(float x){
  return 1.0f/(1.0f + expf(-x));
}

// ---------------- precompute ----------------

__global__ __launch_bounds__(256) void kp_params(
    const float* __restrict__ log_dt, const float* __restrict__ lAr,
    const float* __restrict__ A_im, const float* __restrict__ C_re,
    const float* __restrict__ C_im,
    float* __restrict__ p_ar, float* __restrict__ p_ai,
    float* __restrict__ p_cer, float* __restrict__ p_cei,
    float* __restrict__ p_wtr, float* __restrict__ p_wti)
{
  int idx = blockIdx.x*256 + threadIdx.x;        // NLAY*HCH*N2C
  int lh = idx >> 5;
  float dt = expf(log_dt[lh]);
  float Are = -expf(lAr[idx]);
  float Aim = A_im[idx];
  float ar = Are*dt, ai = Aim*dt;
  float er = expf(ar);
  float wr = er*cosf(ai), wi = er*sinf(ai);
  float inv = 1.0f/(Are*Are + Aim*Aim);
  float tr = ((wr-1.0f)*Are + wi*Aim)*inv;
  float ti = (wi*Are - (wr-1.0f)*Aim)*inv;
  p_cer[idx] = C_re[idx]*tr - C_im[idx]*ti;
  p_cei[idx] = C_re[idx]*ti + C_im[idx]*tr;
  p_ar[idx] = ar; p_ai[idx] = ai;
  float eT = expf(ar*64.0f);
  p_wtr[idx] = eT*cosf(ai*64.0f);
  p_wti[idx] = eT*sinf(ai*64.0f);
}

__global__ __launch_bounds__(256) void kp_kk(
    const float* __restrict__ p_ar, const float* __restrict__ p_ai,
    const float* __restrict__ p_cer, const float* __restrict__ p_cei,
    float* __restrict__ kk)
{
  int idx = blockIdx.x*256 + threadIdx.x;        // NLAY*HCH*TTC
  int d = idx & 63, lh = idx >> 6;
  int base = lh*N2C;
  float fd = (float)d;
  float s = 0.0f;
  for (int n=0; n<N2C; n++){
    float ar = p_ar[base+n], ai = p_ai[base+n];
    float e = expf(ar*fd);
    float pr = e*cosf(ai*fd), pi = e*sinf(ai*fd);
    s += p_cer[base+n]*pr - p_cei[base+n]*pi;
  }
  kk[idx] = 2.0f*s;
}

// A2: per (layer,h): 64x128: cols 0..63 = Toeplitz k[t-j] (j<=t), cols 64..127 = +-2*CW
__global__ __launch_bounds__(256) void kp_A2(
    const float* __restrict__ p_ar, const float* __restrict__ p_ai,
    const float* __restrict__ p_cer, const float* __restrict__ p_cei,
    const float* __restrict__ kk, unsigned short* __restrict__ A2b)
{
  int idx = blockIdx.x*256 + threadIdx.x;        // NLAY*HCH*TTC*128
  int kcol = idx & 127;
  int t = (idx >> 7) & 63;
  int lh = idx >> 13;
  float v;
  if (kcol < 64){
    v = (kcol <= t) ? kk[lh*64 + (t - kcol)] : 0.0f;
  } else {
    int q = kcol - 64, n = q >> 1;
    int p = lh*N2C + n;
    float fp = (float)(t+1);
    float e = expf(p_ar[p]*fp);
    float pr = e*cosf(p_ai[p]*fp), pi = e*sinf(p_ai[p]*fp);
    float cer = p_cer[p], cei = p_cei[p];
    v = (q&1) ? -2.0f*(cer*pi + cei*pr) : 2.0f*(cer*pr - cei*pi);
  }
  A2b[idx] = f2bf(v);
}

// Vm: per (layer,h): 64x64: row q=2n+{re,im}, col j: w_n^{63-j}
__global__ __launch_bounds__(256) void kp_Vm(
    const float* __restrict__ p_ar, const float* __restrict__ p_ai,
    unsigned short* __restrict__ Vmb)
{
  int idx = blockIdx.x*256 + threadIdx.x;        // NLAY*HCH*TTC*TTC
  int j = idx & 63;
  int q = (idx >> 6) & 63;
  int lh = idx >> 12;
  int n = q >> 1;
  int p = lh*N2C + n;
  float fp = (float)(63 - j);
  float e = expf(p_ar[p]*fp);
  float pr = e*cosf(p_ai[p]*fp), pi = e*sinf(p_ai[p]*fp);
  Vmb[idx] = f2bf((q&1) ? pi : pr);
}

// pair-interleaved W + bias: row 2h <- out_w[h], row 2h+1 <- out_w[h+HCH]
__global__ __launch_bounds__(256) void kp_Wp(
    const float* __restrict__ out_w, const float* __restrict__ out_b,
    unsigned short* __restrict__ Wpb, float* __restrict__ bp)
{
  int idx = blockIdx.x*256 + threadIdx.x;        // NLAY*G2C*HCH
  int hcol = idx & 255;
  int g2 = (idx >> 8) & 511;
  int li = idx >> 17;
  int src = (g2 >> 1) + ((g2 & 1) ? HCH : 0);
  Wpb[idx] = f2bf(out_w[((size_t)li*G2C + src)*HCH + hcol]);
  if (hcol == 0) bp[li*G2C + g2] = out_b[li*G2C + src];
}

// ---------------- pre-projection ----------------

__global__ __launch_bounds__(256) void k_preproj(
    const float* __restrict__ x, const float* __restrict__ pre_w,
    const float* __restrict__ pre_b, float* __restrict__ hbuf)
{
  int l = blockIdx.x*256 + threadIdx.x;
  int hc = blockIdx.y, b = blockIdx.z;
  if (l >= LSEQ) return;
  const float* xr = x + (size_t)(b*LSEQ + l)*DIN;
  const float* wr = pre_w + hc*DIN;
  float acc = pre_b[hc];
  #pragma unroll
  for (int d=0; d<DIN; d++) acc += xr[d]*wr[d];
  hbuf[(size_t)(b*HCH + hc)*LSEQ + l] = acc;
}

// ---------------- fused per-row SSM: (BN-apply) + S1 + parallel scan + S3 + gelu ----------------
// One block per (b,h), XCD-remapped so the 8 batches of one hc share an XCD's L2 (Vm/A2 tables).
// u row and states live entirely in LDS; ybuf aliases sE; no per-thread arrays (scan re-reads LDS).
// LDS float4 swizzle: logical float4 index q, phys = q ^ (((q>>4)&7)<<1).

template<int DO_BN>
__global__ __launch_bounds__(320, 4) void k_row(
    const unsigned short* __restrict__ Vm, const unsigned short* __restrict__ A2,
    const float* __restrict__ wtr, const float* __restrict__ wti,
    const float* __restrict__ Dg, float* __restrict__ hbuf,
    const float* __restrict__ scale, const float* __restrict__ shift,
    unsigned short* __restrict__ yg, int layer)
{
  __shared__ float su[5120];
  __shared__ float sE[5120];        // E-states -> S-states -> aliased as ybuf
  int id = blockIdx.x;
  int xcd = id & 7, local = id >> 3;           // co-locate same-hc blocks on one XCD
  int hc = xcd*32 + (local >> 3);
  int b  = local & 7;
  int bh = b*HCH + hc;
  int tid = threadIdx.x, wid = tid>>6, lane = tid&63;
  float* hrow = hbuf + (size_t)bh*LSEQ;
  float bsc = 1.0f, bsh = 0.0f;
  if (DO_BN){ bsc = scale[hc]; bsh = shift[hc]; }
  #pragma unroll
  for (int i=0;i<4;i++){
    int q = tid + i*320;                       // < 1280
    float4 v = {0,0,0,0};
    if (q < 1250) v = *(const float4*)(hrow + q*4);
    if (DO_BN){
      v.x=v.x*bsc+bsh; v.y=v.y*bsc+bsh; v.z=v.z*bsc+bsh; v.w=v.w*bsc+bsh;
      if (q < 1250) *(float4*)(hrow + q*4) = v;
    }
    int p = q ^ (((q>>4)&7)<<1);
    *(float4*)(su + p*4) = v;
  }
  __syncthreads();

  int craw = wid*16 + (lane&15);               // in [0,80)
  int c = craw < NCH ? craw : NCH-1;
  int krow8 = (lane>>4)*8;
  int swz = (c&7)<<1;

  // ---- S1: chunk end-states (zeros for dummy chunk 79) ----
  {
    const unsigned short* Vp = Vm + (size_t)(layer*HCH + hc)*TTC*TTC + (size_t)(lane&15)*TTC;
    f32x4 a0={0,0,0,0},a1={0,0,0,0},a2={0,0,0,0},a3={0,0,0,0};
    #pragma unroll
    for (int ks=0; ks<2; ks++){
      int kb = ks*32 + krow8;
      int p0 = (c*16 + (kb>>2)) ^ swz;
      float4 u0 = *(const float4*)(su + p0*4);
      float4 u1 = *(const float4*)(su + p0*4 + 4);
      bf8v bfr = pack8(u0,u1);
      a0 = MFMA16(*(const bf8v*)(Vp + 0*16*TTC + kb), bfr, a0);
      a1 = MFMA16(*(const bf8v*)(Vp + 1*16*TTC + kb), bfr, a1);
      a2 = MFMA16(*(const bf8v*)(Vp + 2*16*TTC + kb), bfr, a2);
      a3 = MFMA16(*(const bf8v*)(Vp + 3*16*TTC + kb), bfr, a3);
    }
    if (craw >= NCH){
      a0=(f32x4){0,0,0,0}; a1=(f32x4){0,0,0,0};
      a2=(f32x4){0,0,0,0}; a3=(f32x4){0,0,0,0};
    }
    int j0 = craw*16 + (lane>>4);
    int sw2 = (craw&7)<<1;
    *(f32x4*)(sE + (size_t)((j0+ 0)^sw2)*4) = a0;
    *(f32x4*)(sE + (size_t)((j0+ 4)^sw2)*4) = a1;
    *(f32x4*)(sE + (size_t)((j0+ 8)^sw2)*4) = a2;
    *(f32x4*)(sE + (size_t)((j0+12)^sw2)*4) = a3;
  }
  __syncthreads();

  // ---- parallel blocked scan: 256 threads = 32 components x 8 chunk-groups, no arrays ----
  if (tid < 256){
    int n = tid >> 3, g = tid & 7;
    float wr = wtr[(layer*HCH+hc)*N2C + n];
    float wi = wti[(layer*HCH+hc)*N2C + n];
    int c0 = g*10;
    // group total T over 10 chunks (chunk 79 slot holds zeros)
    float tr_=0.0f, ti_=0.0f;
    #pragma unroll
    for (int k=0;k<10;k++){
      int cc = c0 + k;
      int p = ((cc*16 + (n>>1)) ^ ((cc&7)<<1))*4 + (n&1)*2;
      float2 e = *(float2*)(sE + p);
      float nr = wr*tr_ - wi*ti_ + e.x;
      ti_ = wr*ti_ + wi*tr_ + e.y;
      tr_ = nr;
    }
    // A = w^10 (group multiplier), B = T; affine prefix-compose across g
    float a2r = wr*wr - wi*wi,      a2i = 2.0f*wr*wi;
    float a4r = a2r*a2r - a2i*a2i,  a4i = 2.0f*a2r*a2i;
    float a8r = a4r*a4r - a4i*a4i,  a8i = 2.0f*a4r*a4i;
    float Ar = a8r*a2r - a8i*a2i,   Ai = a8r*a2i + a8i*a2r;
    float Br = tr_, Bi = ti_;
    #pragma unroll
    for (int st=1; st<8; st<<=1){
      float Ar2 = __shfl_up(Ar, st), Ai2 = __shfl_up(Ai, st);
      float Br2 = __shfl_up(Br, st), Bi2 = __shfl_up(Bi, st);
      if (g >= st){
        float nAr = Ar*Ar2 - Ai*Ai2;
        float nAi = Ar*Ai2 + Ai*Ar2;
        float nBr = Ar*Br2 - Ai*Bi2 + Br;
        float nBi = Ar*Bi2 + Ai*Br2 + Bi;
        Ar=nAr; Ai=nAi; Br=nBr; Bi=nBi;
      }
    }
    float Pr = __shfl_up(Br, 1), Pi = __shfl_up(Bi, 1);
    if (g == 0){ Pr = 0.0f; Pi = 0.0f; }
    // replay: re-read e, write entering-state per chunk
    #pragma unroll
    for (int k=0;k<10;k++){
      int cc = c0 + k;
      int p = ((cc*16 + (n>>1)) ^ ((cc&7)<<1))*4 + (n&1)*2;
      float2 e = *(float2*)(sE + p);
      *(float2*)(sE + p) = make_float2(Pr, Pi);
      float nr = wr*Pr - wi*Pi + e.x;
      Pi = wr*Pi + wi*Pr + e.y;
      Pr = nr;
    }
  }
  __syncthreads();

  // ---- S3: Toeplitz conv + state correction (hi/lo split) ----
  f32x4 acc0={0,0,0,0},acc1={0,0,0,0},acc2={0,0,0,0},acc3={0,0,0,0};
  {
    const unsigned short* Ap = A2 + (size_t)(layer*HCH + hc)*TTC*128 + (size_t)(lane&15)*128;
    #pragma unroll
    for (int ks=0; ks<2; ks++){
      int kb = ks*32 + krow8;
      int p0 = (c*16 + (kb>>2)) ^ swz;
      float4 u0 = *(const float4*)(su + p0*4);
      float4 u1 = *(const float4*)(su + p0*4 + 4);
      bf8v bfr = pack8(u0,u1);
      acc0 = MFMA16(*(const bf8v*)(Ap + 0*16*128 + kb), bfr, acc0);
      acc1 = MFMA16(*(const bf8v*)(Ap + 1*16*128 + kb), bfr, acc1);
      acc2 = MFMA16(*(const bf8v*)(Ap + 2*16*128 + kb), bfr, acc2);
      acc3 = MFMA16(*(const bf8v*)(Ap + 3*16*128 + kb), bfr, acc3);
    }
    #pragma unroll
    for (int ks=2; ks<4; ks++){
      int kb = ks*32 + krow8;
      int p0 = (c*16 + ((kb-64)>>2)) ^ swz;
      float4 s0 = *(const float4*)(sE + p0*4);
      float4 s1 = *(const float4*)(sE + p0*4 + 4);
      bf8v bhv = pack8(s0,s1);
      acc0 = MFMA16(*(const bf8v*)(Ap + 0*16*128 + kb), bhv, acc0);
      acc1 = MFMA16(*(const bf8v*)(Ap + 1*16*128 + kb), bhv, acc1);
      acc2 = MFMA16(*(const bf8v*)(Ap + 2*16*128 + kb), bhv, acc2);
      acc3 = MFMA16(*(const bf8v*)(Ap + 3*16*128 + kb), bhv, acc3);
      float4 r0, r1;
      r0.x = s0.x - bf2f(f2bf(s0.x)); r0.y = s0.y - bf2f(f2bf(s0.y));
      r0.z = s0.z - bf2f(f2bf(s0.z)); r0.w = s0.w - bf2f(f2bf(s0.w));
      r1.x = s1.x - bf2f(f2bf(s1.x)); r1.y = s1.y - bf2f(f2bf(s1.y));
      r1.z = s1.z - bf2f(f2bf(s1.z)); r1.w = s1.w - bf2f(f2bf(s1.w));
      bf8v blv = pack8(r0,r1);
      acc0 = MFMA16(*(const bf8v*)(Ap + 0*16*128 + kb), blv, acc0);
      acc1 = MFMA16(*(const bf8v*)(Ap + 1*16*128 + kb), blv, acc1);
      acc2 = MFMA16(*(const bf8v*)(Ap + 2*16*128 + kb), blv, acc2);
      acc3 = MFMA16(*(const bf8v*)(Ap + 3*16*128 + kb), blv, acc3);
    }
  }
  __syncthreads();   // all sE reads done; safe to overwrite as ybuf

  {
    float* ybuf = sE;
    float Dv = Dg[layer*HCH + hc];
    int tq = (lane>>4)*4;
    int qb = craw*16 + (tq>>2);
    int sw2 = (craw&7)<<1;
    float4 u4, o4;
    u4 = *(const float4*)(su + (size_t)((qb+ 0)^sw2)*4);
    o4.x = gelu_f(acc0[0] + Dv*u4.x); o4.y = gelu_f(acc0[1] + Dv*u4.y);
    o4.z = gelu_f(acc0[2] + Dv*u4.z); o4.w = gelu_f(acc0[3] + Dv*u4.w);
    *(float4*)(ybuf + (size_t)((qb+ 0)^sw2)*4) = o4;
    u4 = *(const float4*)(su + (size_t)((qb+ 4)^sw2)*4);
    o4.x = gelu_f(acc1[0] + Dv*u4.x); o4.y = gelu_f(acc1[1] + Dv*u4.y);
    o4.z = gelu_f(acc1[2] + Dv*u4.z); o4.w = gelu_f(acc1[3] + Dv*u4.w);
    *(float4*)(ybuf + (size_t)((qb+ 4)^sw2)*4) = o4;
    u4 = *(const float4*)(su + (size_t)((qb+ 8)^sw2)*4);
    o4.x = gelu_f(acc2[0] + Dv*u4.x); o4.y = gelu_f(acc2[1] + Dv*u4.y);
    o4.z = gelu_f(acc2[2] + Dv*u4.z); o4.w = gelu_f(acc2[3] + Dv*u4.w);
    *(float4*)(ybuf + (size_t)((qb+ 8)^sw2)*4) = o4;
    u4 = *(const float4*)(su + (size_t)((qb+12)^sw2)*4);
    o4.x = gelu_f(acc3[0] + Dv*u4.x); o4.y = gelu_f(acc3[1] + Dv*u4.y);
    o4.z = gelu_f(acc3[2] + Dv*u4.z); o4.w = gelu_f(acc3[3] + Dv*u4.w);
    *(float4*)(ybuf + (size_t)((qb+12)^sw2)*4) = o4;
  }
  __syncthreads();
  unsigned short* ygp = yg + (size_t)bh*LSEQ;
  #pragma unroll
  for (int pass=0; pass<2; pass++){
    int l0 = (pass*320 + tid)*8;
    if (l0 < LSEQ){
      int q0 = l0 >> 2;                        // even
      int p0 = q0 ^ (((q0>>4)&7)<<1);
      int q1 = q0 + 1;
      int p1 = q1 ^ (((q1>>4)&7)<<1);
      float4 v0 = *(const float4*)(sE + (size_t)p0*4);
      float4 v1 = *(const float4*)(sE + (size_t)p1*4);
      us8v o;
      o[0]=f2bf(v0.x); o[1]=f2bf(v0.y); o[2]=f2bf(v0.z); o[3]=f2bf(v0.w);
      o[4]=f2bf(v1.x); o[5]=f2bf(v1.y); o[6]=f2bf(v1.z); o[7]=f2bf(v1.w);
      *(us8v*)(ygp + l0) = o;
    }
  }
}

// ---------------- transpose yg[b][h][l] -> ygT[b][l][h] (bf16) ----------------

__global__ __launch_bounds__(256) void k_T(
    const unsigned short* __restrict__ yg, unsigned short* __restrict__ ygT)
{
  __shared__ unsigned short tile[64][72];
  int b = blockIdx.z, h0 = blockIdx.y*64, l0 = blockIdx.x*64;
  int tid = threadIdx.x;
  #pragma unroll
  for (int i=0;i<2;i++){
    int lidx = tid + i*256;
    int row = lidx>>3, c8 = (lidx&7)*8;
    us8v v = 0;
    if (l0 + c8 < LSEQ)
      v = *(const us8v*)(yg + (size_t)(b*HCH + h0 + row)*LSEQ + l0 + c8);
    *(us8v*)(&tile[row][c8]) = v;
  }
  __syncthreads();
  #pragma unroll
  for (int i=0;i<2;i++){
    int widx = tid + i*256;
    int r = widx>>3, h8 = (widx&7)*8;
    int l = l0 + r;
    us8v o = 0;
    if (l < LSEQ){
      #pragma unroll
      for (int e=0;e<8;e++) o[e] = tile[h8+e][r];
    }
    *(us8v*)(ygT + ((size_t)b*LPAD + l)*HCH + h0 + h8) = o;
  }
}

// ---------------- GEMM + GLU + residual + (BN stats): streaming K-resident ----------------

static __device__ __forceinline__ void stageA(
    const unsigned short* __restrict__ g, unsigned short* sbuf, int tid)
{
  #pragma unroll
  for (int i=0;i<8;i++){
    int p = i*256 + tid;                 // [0,2048) 16B-chunks
    int row = p>>5, kc = p&31;
    int kcl = kc ^ (row&7);
    const unsigned short* ga = g + (size_t)row*HCH + kcl*8;
    __builtin_amdgcn_global_load_lds(
        (const __attribute__((address_space(1))) void*)ga,
        (__attribute__((address_space(3))) void*)(sbuf + p*8),
        16, 0, 0);
  }
}
static __device__ __forceinline__ void stageB(
    const unsigned short* __restrict__ g, unsigned short* sbuf, int tid)
{
  #pragma unroll
  for (int i=0;i<4;i++){
    int p = i*256 + tid;                 // [0,1024)
    int row = p>>5, kc = p&31;
    int kcl = kc ^ (row&7);
    const unsigned short* ga = g + (size_t)row*HCH + kcl*8;
    __builtin_amdgcn_global_load_lds(
        (const __attribute__((address_space(1))) void*)ga,
        (__attribute__((address_space(3))) void*)(sbuf + p*8),
        16, 0, 0);
  }
}
static __device__ __forceinline__ bf8v ldsF(const unsigned short* sbuf, int row, int k0){
  int byte = (row<<9) + (k0<<1);
  byte ^= ((row&7)<<4);
  return *(const bf8v*)((const char*)sbuf + byte);
}

template<int DO_STATS>
__global__ __launch_bounds__(256, 2) void k_gemm(
    const unsigned short* __restrict__ Wp, const float* __restrict__ bp,
    const unsigned short* __restrict__ ygT, float* __restrict__ hbuf,
    float* __restrict__ bnsum, float* __restrict__ bnsq, int layer)
{
  __shared__ unsigned short As[64*256];      // 32KB
  __shared__ unsigned short Bs[3][32*256];   // 48KB
  int id = blockIdx.x;
  int x = id & 7, s = id >> 3;
  int gt = s & 7;
  int q = x*8 + (s>>3);                      // [0,64): co-XCD set shares (b,lg)
  int b = q >> 3, lg = q & 7;
  int l0 = lg*640;

  int tid = threadIdx.x, wid = tid>>6, lane = tid&63;
  int wm = wid>>1, wn = wid&1;
  int colA = lane&15, krow8 = (lane>>4)*8;

  const unsigned short* Wt = Wp + (size_t)layer*G2C*HCH + (size_t)(gt*64)*HCH;
  const unsigned short* Yb = ygT + (size_t)b*LPAD*HCH;

  stageA(Wt, As, tid);
  stageB(Yb + (size_t)l0*HCH,      Bs[0], tid);
  stageB(Yb + (size_t)(l0+32)*HCH, Bs[1], tid);

  float4 bias4[2]; int hc0[2];
  #pragma unroll
  for (int m=0;m<2;m++){
    int g2r4 = gt*64 + wm*32 + m*16 + (lane>>4)*4;
    bias4[m] = *(const float4*)(bp + layer*G2C + g2r4);
    hc0[m] = g2r4 >> 1;
  }
  float sacc[4], qacc[4];
  if (DO_STATS){
    #pragma unroll
    for (int i=0;i<4;i++){ sacc[i]=0.0f; qacc[i]=0.0f; }
  }

  const int NT = 20;
  for (int t=0; t<NT; t++){
    __builtin_amdgcn_s_barrier();            // all waves done reading slot (t+2)%3's old tile
    if (t+2 < NT)
      stageB(Yb + (size_t)(l0 + (t+2)*32)*HCH, Bs[(t+2)%3], tid);
    if (t+2 < NT)      asm volatile("s_waitcnt vmcnt(8)" ::: "memory");
    else if (t+1 < NT) asm volatile("s_waitcnt vmcnt(4)" ::: "memory");
    else               asm volatile("s_waitcnt vmcnt(0)" ::: "memory");
    __builtin_amdgcn_s_barrier();            // B_t visible to all
    const unsigned short* Bc = Bs[t%3];
    f32x4 acc0 = (f32x4){0,0,0,0}, acc1 = (f32x4){0,0,0,0};
    #pragma unroll
    for (int ks=0; ks<8; ks++){
      int k0 = ks*32 + krow8;
      bf8v fb  = ldsF(Bc, wn*16 + colA, k0);
      bf8v fa0 = ldsF(As, wm*32 + colA, k0);
      bf8v fa1 = ldsF(As, wm*32 + 16 + colA, k0);
      acc0 = MFMA16(fa0, fb, acc0);
      acc1 = MFMA16(fa1, fb, acc1);
    }
    int l = l0 + t*32 + wn*16 + colA;
    #pragma unroll
    for (int m=0;m<2;m++){
      f32x4 av = m ? acc1 : acc0;
      float a0 = av[0] + bias4[m].x;
      float g0 = av[1] + bias4[m].y;
      float a1 = av[2] + bias4[m].z;
      float g1 = av[3] + bias4[m].w;
      float z0 = a0 * sigm(g0);
      float z1 = a1 * sigm(g1);
      float r0 = 0.0f, r1 = 0.0f;
      if (l < LSEQ){
        float* pp0 = hbuf + ((size_t)(b*HCH + hc0[m]))*LSEQ + l;
        float* pp1 = pp0 + LSEQ;
        r0 = z0 + pp0[0]; pp0[0] = r0;
        r1 = z1 + pp1[0]; pp1[0] = r1;
      }
      if (DO_STATS){
        sacc[m*2+0] += r0; qacc[m*2+0] += r0*r0;
        sacc[m*2+1] += r1; qacc[m*2+1] += r1*r1;
      }
    }
  }

  if (DO_STATS){
    #pragma unroll
    for (int m=0;m<2;m++){
      #pragma unroll
      for (int zr=0; zr<2; zr++){
        float sv = sacc[m*2+zr], qv = qacc[m*2+zr];
        sv += __shfl_xor(sv,1); qv += __shfl_xor(qv,1);
        sv += __shfl_xor(sv,2); qv += __shfl_xor(qv,2);
        sv += __shfl_xor(sv,4); qv += __shfl_xor(qv,4);
        sv += __shfl_xor(sv,8); qv += __shfl_xor(qv,8);
        if ((lane&15)==0){
          atomicAdd(&bnsum[hc0[m]+zr], sv);
          atomicAdd(&bnsq[hc0[m]+zr], qv);
        }
      }
    }
  }
}

// ---------------- batchnorm finalize (apply is fused into next k_row) ----------------

__global__ void k_bnfin(const float* __restrict__ bnsum, const float* __restrict__ bnsq,
    const float* __restrict__ gam, const float* __restrict__ bet,
    float* __restrict__ scale, float* __restrict__ shift, int bnidx)
{
  int hc = threadIdx.x;
  const float inv = 1.0f/40000.0f;
  float mean = bnsum[hc]*inv;
  float var = bnsq[hc]*inv - mean*mean;
  float sc = gam[bnidx*HCH + hc] * rsqrtf(var + 1e-5f);
  scale[hc] = sc;
  shift[hc] = bet[bnidx*HCH + hc] - mean*sc;
}

// ---------------- final transpose h[b][h][l] -> out[b][l][h] ----------------

__global__ __launch_bounds__(256) void k_outT(const float* __restrict__ hbuf,
    float* __restrict__ out)
{
  __shared__ float tile[64][65];
  int b = blockIdx.z, h0 = blockIdx.y*64, l0 = blockIdx.x*64;
  int tid = threadIdx.x;
  #pragma unroll
  for (int i=0;i<4;i++){
    int lidx = tid + i*256;
    int row = lidx>>4, c4 = (lidx&15)*4;
    float4 v = {0,0,0,0};
    if (l0 + c4 < LSEQ)
      v = *(const float4*)(hbuf + (size_t)(b*HCH + h0 + row)*LSEQ + l0 + c4);
    tile[row][c4+0]=v.x; tile[row][c4+1]=v.y; tile[row][c4+2]=v.z; tile[row][c4+3]=v.w;
  }
  __syncthreads();
  #pragma unroll
  for (int i=0;i<4;i++){
    int widx = tid + i*256;
    int r = widx>>4, h4 = (widx&15)*4;
    int l = l0 + r;
    if (l < LSEQ){
      float4 o = { tile[h4+0][r], tile[h4+1][r], tile[h4+2][r], tile[h4+3][r] };
      *(float4*)(out + ((size_t)(b*LSEQ) + l)*HCH + h0 + h4) = o;
    }
  }
}

// ---------------- host ----------------

extern "C" void kernel_launch(void* const* d_in, const int* in_sizes, int n_in,
                              void* d_out, int out_size, void* d_ws, size_t ws_size,
                              hipStream_t stream)
{
  (void)in_sizes; (void)n_in; (void)out_size; (void)ws_size;
  const float* x      = (const float*)d_in[0];
  const float* pre_w  = (const float*)d_in[1];
  const float* pre_b  = (const float*)d_in[2];
  const float* log_dt = (const float*)d_in[3];
  const float* C_re   = (const float*)d_in[4];
  const float* C_im   = (const float*)d_in[5];
  const float* lAr    = (const float*)d_in[6];
  const float* A_im   = (const float*)d_in[7];
  const float* Dg     = (const float*)d_in[8];
  const float* out_w  = (const float*)d_in[9];
  const float* out_b  = (const float*)d_in[10];
  const float* gam    = (const float*)d_in[11];
  const float* bet    = (const float*)d_in[12];
  float* out = (float*)d_out;

  char* ws = (char*)d_ws;
  size_t off = 0;
  auto alloc = [&](size_t bytes)->char*{
    char* p = ws + off;
    off += (bytes + 255) & ~(size_t)255;
    return p;
  };
  float*          hbuf  = (float*)         alloc((size_t)(NB*HCH*LSEQ + 8192)*4);
  unsigned short* yg    = (unsigned short*)alloc((size_t)(NB*HCH*LSEQ + 64)*2);
  unsigned short* ygT   = (unsigned short*)alloc((size_t)NB*LPAD*HCH*2);
  float*          p_ar  = (float*)         alloc((size_t)NLAY*HCH*N2C*4);
  float*          p_ai  = (float*)         alloc((size_t)NLAY*HCH*N2C*4);
  float*          p_cer = (float*)         alloc((size_t)NLAY*HCH*N2C*4);
  float*          p_cei = (float*)         alloc((size_t)NLAY*HCH*N2C*4);
  float*          p_wtr = (float*)         alloc((size_t)NLAY*HCH*N2C*4);
  float*          p_wti = (float*)         alloc((size_t)NLAY*HCH*N2C*4);
  float*          kk    = (float*)         alloc((size_t)NLAY*HCH*TTC*4);
  unsigned short* A2b   = (unsigned short*)alloc((size_t)NLAY*HCH*TTC*128*2);
  unsigned short* Vmb   = (unsigned short*)alloc((size_t)NLAY*HCH*TTC*TTC*2);
  unsigned short* Wpb   = (unsigned short*)alloc((size_t)NLAY*G2C*HCH*2);
  float*          bp    = (float*)         alloc((size_t)NLAY*G2C*4);
  float*          bnst  = (float*)         alloc((size_t)4*HCH*4);
  float* bnsum = bnst, *bnsq = bnst + HCH, *bnscale = bnst + 2*HCH, *bnshift = bnst + 3*HCH;

  kp_params<<<(NLAY*HCH*N2C)/256, 256, 0, stream>>>(log_dt, lAr, A_im, C_re, C_im,
      p_ar, p_ai, p_cer, p_cei, p_wtr, p_wti);
  kp_kk<<<(NLAY*HCH*TTC)/256, 256, 0, stream>>>(p_ar, p_ai, p_cer, p_cei, kk);
  kp_A2<<<(NLAY*HCH*TTC*128)/256, 256, 0, stream>>>(p_ar, p_ai, p_cer, p_cei, kk, A2b);
  kp_Vm<<<(NLAY*HCH*TTC*TTC)/256, 256, 0, stream>>>(p_ar, p_ai, Vmb);
  kp_Wp<<<(NLAY*G2C*HCH)/256, 256, 0, stream>>>(out_w, out_b, Wpb, bp);

  k_preproj<<<dim3(20, HCH, NB), 256, 0, stream>>>(x, pre_w, pre_b, hbuf);

  for (int layer=0; layer<NLAY; layer++){
    if (layer & 1)
      k_row<1><<<NB*HCH, 320, 0, stream>>>(Vmb, A2b, p_wtr, p_wti, Dg, hbuf,
                                           bnscale, bnshift, yg, layer);
    else
      k_row<0><<<NB*HCH, 320, 0, stream>>>(Vmb, A2b, p_wtr, p_wti, Dg, hbuf,
                                           bnscale, bnshift, yg, layer);
    k_T<<<dim3(LPAD/64, HCH/64, NB), 256, 0, stream>>>(yg, ygT);
    if ((layer & 1) == 0){
      hipMemsetAsync(bnsum, 0, 2*HCH*sizeof(float), stream);
      k_gemm<1><<<512, 256, 0, stream>>>(Wpb, bp, ygT, hbuf, bnsum, bnsq, layer);
      k_bnfin<<<1, HCH, 0, stream>>>(bnsum, bnsq, gam, bet, bnscale, bnshift, layer/2);
    } else {
      k_gemm<0><<<512, 256, 0, stream>>>(Wpb, bp, ygT, hbuf, bnsum, bnsq, layer);
    }
  }
  k_outT<<<dim3(79, HCH/64, NB), 256, 0, stream>>>(hbuf, out);
}

// Round 7
// 805.667 us; speedup vs baseline: 1.0556x; 1.0556x over previous
//
#include <hip/hip_runtime.h>
#include <hip/hip_bf16.h>
#include <math.h>

#define NB 8
#define LSEQ 5000
#define DIN 12
#define HCH 256
#define N2C 32
#define NLAY 6
#define G2C 512
#define TTC 64
#define NCH 79

typedef __attribute__((ext_vector_type(8))) short bf8v;
typedef __attribute__((ext_vector_type(8))) unsigned short us8v;
typedef __attribute__((ext_vector_type(4))) unsigned short us4v;
typedef __attribute__((ext_vector_type(4))) float f32x4;

#define MFMA16(a,b,c) __builtin_amdgcn_mfma_f32_16x16x32_bf16((a),(b),(c),0,0,0)

static __device__ __forceinline__ unsigned short f2bf(float f){
  unsigned int u = __float_as_uint(f);
  u = u + 0x7FFFu + ((u >> 16) & 1u);
  return (unsigned short)(u >> 16);
}
static __device__ __forceinline__ float bf2f(unsigned short s){
  return __uint_as_float(((unsigned int)s) << 16);
}
static __device__ __forceinline__ bf8v pack8(float4 a, float4 b){
  bf8v r;
  r[0]=(short)f2bf(a.x); r[1]=(short)f2bf(a.y); r[2]=(short)f2bf(a.z); r[3]=(short)f2bf(a.w);
  r[4]=(short)f2bf(b.x); r[5]=(short)f2bf(b.y); r[6]=(short)f2bf(b.z); r[7]=(short)f2bf(b.w);
  return r;
}
static __device__ __forceinline__ float gelu_f(float x){
  return 0.5f*x*(1.0f + erff(x*0.70710678118654752f));
}
static __device__ __forceinline__ float sigm(float x){
  return 1.0f/(1.0f + expf(-x));
}

// ---------------- precompute ----------------

__global__ __launch_bounds__(256) void kp_params(
    const float* __restrict__ log_dt, const float* __restrict__ lAr,
    const float* __restrict__ A_im, const float* __restrict__ C_re,
    const float* __restrict__ C_im,
    float* __restrict__ p_ar, float* __restrict__ p_ai,
    float* __restrict__ p_cer, float* __restrict__ p_cei,
    float* __restrict__ p_wtr, float* __restrict__ p_wti)
{
  int idx = blockIdx.x*256 + threadIdx.x;
  int lh = idx >> 5;
  float dt = expf(log_dt[lh]);
  float Are = -expf(lAr[idx]);
  float Aim = A_im[idx];
  float ar = Are*dt, ai = Aim*dt;
  float er = expf(ar);
  float wr = er*cosf(ai), wi = er*sinf(ai);
  float inv = 1.0f/(Are*Are + Aim*Aim);
  float tr = ((wr-1.0f)*Are + wi*Aim)*inv;
  float ti = (wi*Are - (wr-1.0f)*Aim)*inv;
  p_cer[idx] = C_re[idx]*tr - C_im[idx]*ti;
  p_cei[idx] = C_re[idx]*ti + C_im[idx]*tr;
  p_ar[idx] = ar; p_ai[idx] = ai;
  float eT = expf(ar*64.0f);
  p_wtr[idx] = eT*cosf(ai*64.0f);
  p_wti[idx] = eT*sinf(ai*64.0f);
}

__global__ __launch_bounds__(256) void kp_kk(
    const float* __restrict__ p_ar, const float* __restrict__ p_ai,
    const float* __restrict__ p_cer, const float* __restrict__ p_cei,
    float* __restrict__ kk)
{
  int idx = blockIdx.x*256 + threadIdx.x;
  int d = idx & 63, lh = idx >> 6;
  int base = lh*N2C;
  float fd = (float)d;
  float s = 0.0f;
  for (int n=0; n<N2C; n++){
    float ar = p_ar[base+n], ai = p_ai[base+n];
    float e = expf(ar*fd);
    float pr = e*cosf(ai*fd), pi = e*sinf(ai*fd);
    s += p_cer[base+n]*pr - p_cei[base+n]*pi;
  }
  kk[idx] = 2.0f*s;
}

__global__ __launch_bounds__(256) void kp_A2(
    const float* __restrict__ p_ar, const float* __restrict__ p_ai,
    const float* __restrict__ p_cer, const float* __restrict__ p_cei,
    const float* __restrict__ kk, unsigned short* __restrict__ A2b)
{
  int idx = blockIdx.x*256 + threadIdx.x;
  int kcol = idx & 127;
  int t = (idx >> 7) & 63;
  int lh = idx >> 13;
  float v;
  if (kcol < 64){
    v = (kcol <= t) ? kk[lh*64 + (t - kcol)] : 0.0f;
  } else {
    int q = kcol - 64, n = q >> 1;
    int p = lh*N2C + n;
    float fp = (float)(t+1);
    float e = expf(p_ar[p]*fp);
    float pr = e*cosf(p_ai[p]*fp), pi = e*sinf(p_ai[p]*fp);
    float cer = p_cer[p], cei = p_cei[p];
    v = (q&1) ? -2.0f*(cer*pi + cei*pr) : 2.0f*(cer*pr - cei*pi);
  }
  A2b[idx] = f2bf(v);
}

__global__ __launch_bounds__(256) void kp_Vm(
    const float* __restrict__ p_ar, const float* __restrict__ p_ai,
    unsigned short* __restrict__ Vmb)
{
  int idx = blockIdx.x*256 + threadIdx.x;
  int j = idx & 63;
  int q = (idx >> 6) & 63;
  int lh = idx >> 12;
  int n = q >> 1;
  int p = lh*N2C + n;
  float fp = (float)(63 - j);
  float e = expf(p_ar[p]*fp);
  float pr = e*cosf(p_ai[p]*fp), pi = e*sinf(p_ai[p]*fp);
  Vmb[idx] = f2bf((q&1) ? pi : pr);
}

__global__ __launch_bounds__(256) void kp_Wp(
    const float* __restrict__ out_w, const float* __restrict__ out_b,
    unsigned short* __restrict__ Wpb, float* __restrict__ bp)
{
  int idx = blockIdx.x*256 + threadIdx.x;
  int hcol = idx & 255;
  int g2 = (idx >> 8) & 511;
  int li = idx >> 17;
  int src = (g2 >> 1) + ((g2 & 1) ? HCH : 0);
  Wpb[idx] = f2bf(out_w[((size_t)li*G2C + src)*HCH + hcol]);
  if (hcol == 0) bp[li*G2C + g2] = out_b[li*G2C + src];
}

// ---------------- pre-projection ----------------

__global__ __launch_bounds__(256) void k_preproj(
    const float* __restrict__ x, const float* __restrict__ pre_w,
    const float* __restrict__ pre_b, float* __restrict__ hbuf)
{
  int l = blockIdx.x*256 + threadIdx.x;
  int hc = blockIdx.y, b = blockIdx.z;
  if (l >= LSEQ) return;
  const float* xr = x + (size_t)(b*LSEQ + l)*DIN;
  const float* wr = pre_w + hc*DIN;
  float acc = pre_b[hc];
  #pragma unroll
  for (int d=0; d<DIN; d++) acc += xr[d]*wr[d];
  hbuf[(size_t)(b*HCH + hc)*LSEQ + l] = acc;
}

// ---------------- fused per-row SSM: (BN-read) + S1 + parallel scan + S3 + gelu ----------------
// u packed bf16 in LDS (MFMA-ready). sE float4 swizzle: phys4(q) = q ^ ((q>>4)&7).
// suh 16B-chunk swizzle: pc(q2) = q2 ^ ((q2>>3)&7). No hbuf writeback (lazy BN).

template<int DO_BN>
__global__ __launch_bounds__(320, 4) void k_row(
    const unsigned short* __restrict__ Vm, const unsigned short* __restrict__ A2,
    const float* __restrict__ wtr, const float* __restrict__ wti,
    const float* __restrict__ Dg, const float* __restrict__ hbuf,
    const float* __restrict__ scale, const float* __restrict__ shift,
    unsigned short* __restrict__ yg, int layer)
{
  __shared__ unsigned short suh[5120];   // 10KB packed bf16 u
  __shared__ float sE[5120];             // 20KB states, later ybuf alias
  int id = blockIdx.x;
  int xcd = id & 7, local = id >> 3;
  int hc = xcd*32 + (local >> 3);
  int b  = local & 7;
  int bh = b*HCH + hc;
  int tid = threadIdx.x, wid = tid>>6, lane = tid&63;
  const float* hrow = hbuf + (size_t)bh*LSEQ;
  float bsc = 1.0f, bsh = 0.0f;
  if (DO_BN){ bsc = scale[hc]; bsh = shift[hc]; }
  #pragma unroll
  for (int i=0;i<4;i++){
    int idx = tid + i*320;                       // < 1280
    float4 v = {0,0,0,0};
    if (idx < 1250) v = *(const float4*)(hrow + idx*4);
    if (DO_BN){
      v.x=fmaf(v.x,bsc,bsh); v.y=fmaf(v.y,bsc,bsh);
      v.z=fmaf(v.z,bsc,bsh); v.w=fmaf(v.w,bsc,bsh);
    }
    us4v pk;
    pk[0]=f2bf(v.x); pk[1]=f2bf(v.y); pk[2]=f2bf(v.z); pk[3]=f2bf(v.w);
    int q2 = idx>>1;
    int pq = q2 ^ ((q2>>3)&7);
    *(us4v*)(suh + pq*8 + (idx&1)*4) = pk;
  }
  __syncthreads();

  int craw = wid*16 + (lane&15);               // [0,80)
  int c = craw < NCH ? craw : NCH-1;
  int krow8 = (lane>>4)*8;
  int swz = c&7;

  // ---- S1: chunk end-states ----
  {
    const unsigned short* Vp = Vm + (size_t)(layer*HCH + hc)*TTC*TTC + (size_t)(lane&15)*TTC;
    f32x4 a0={0,0,0,0},a1={0,0,0,0},a2={0,0,0,0},a3={0,0,0,0};
    #pragma unroll
    for (int ks=0; ks<2; ks++){
      int kb = ks*32 + krow8;
      bf8v bfr = *(const bf8v*)(suh + (size_t)((c*8 + (kb>>3)) ^ swz)*8);
      a0 = MFMA16(*(const bf8v*)(Vp + 0*16*TTC + kb), bfr, a0);
      a1 = MFMA16(*(const bf8v*)(Vp + 1*16*TTC + kb), bfr, a1);
      a2 = MFMA16(*(const bf8v*)(Vp + 2*16*TTC + kb), bfr, a2);
      a3 = MFMA16(*(const bf8v*)(Vp + 3*16*TTC + kb), bfr, a3);
    }
    if (craw >= NCH){
      a0=(f32x4){0,0,0,0}; a1=(f32x4){0,0,0,0};
      a2=(f32x4){0,0,0,0}; a3=(f32x4){0,0,0,0};
    }
    int j0 = craw*16 + (lane>>4);
    int sw2 = craw&7;
    *(f32x4*)(sE + (size_t)((j0+ 0)^sw2)*4) = a0;
    *(f32x4*)(sE + (size_t)((j0+ 4)^sw2)*4) = a1;
    *(f32x4*)(sE + (size_t)((j0+ 8)^sw2)*4) = a2;
    *(f32x4*)(sE + (size_t)((j0+12)^sw2)*4) = a3;
  }
  __syncthreads();

  // ---- parallel blocked scan: 256 threads = 32 comps x 8 groups ----
  if (tid < 256){
    int n = tid >> 3, g = tid & 7;
    float wr = wtr[(layer*HCH+hc)*N2C + n];
    float wi = wti[(layer*HCH+hc)*N2C + n];
    int c0 = g*10;
    float tr_=0.0f, ti_=0.0f;
    #pragma unroll
    for (int k=0;k<10;k++){
      int cc = c0 + k;
      int p = ((cc*16 + (n>>1)) ^ (cc&7))*4 + (n&1)*2;
      float2 e = *(float2*)(sE + p);
      float nr = wr*tr_ - wi*ti_ + e.x;
      ti_ = wr*ti_ + wi*tr_ + e.y;
      tr_ = nr;
    }
    float a2r = wr*wr - wi*wi,      a2i = 2.0f*wr*wi;
    float a4r = a2r*a2r - a2i*a2i,  a4i = 2.0f*a2r*a2i;
    float a8r = a4r*a4r - a4i*a4i,  a8i = 2.0f*a4r*a4i;
    float Ar = a8r*a2r - a8i*a2i,   Ai = a8r*a2i + a8i*a2r;
    float Br = tr_, Bi = ti_;
    #pragma unroll
    for (int st=1; st<8; st<<=1){
      float Ar2 = __shfl_up(Ar, st), Ai2 = __shfl_up(Ai, st);
      float Br2 = __shfl_up(Br, st), Bi2 = __shfl_up(Bi, st);
      if (g >= st){
        float nAr = Ar*Ar2 - Ai*Ai2;
        float nAi = Ar*Ai2 + Ai*Ar2;
        float nBr = Ar*Br2 - Ai*Bi2 + Br;
        float nBi = Ar*Bi2 + Ai*Br2 + Bi;
        Ar=nAr; Ai=nAi; Br=nBr; Bi=nBi;
      }
    }
    float Pr = __shfl_up(Br, 1), Pi = __shfl_up(Bi, 1);
    if (g == 0){ Pr = 0.0f; Pi = 0.0f; }
    #pragma unroll
    for (int k=0;k<10;k++){
      int cc = c0 + k;
      int p = ((cc*16 + (n>>1)) ^ (cc&7))*4 + (n&1)*2;
      float2 e = *(float2*)(sE + p);
      *(float2*)(sE + p) = make_float2(Pr, Pi);
      float nr = wr*Pr - wi*Pi + e.x;
      Pi = wr*Pi + wi*Pr + e.y;
      Pr = nr;
    }
  }
  __syncthreads();

  // ---- S3: Toeplitz conv + state correction (hi/lo split) ----
  f32x4 acc0={0,0,0,0},acc1={0,0,0,0},acc2={0,0,0,0},acc3={0,0,0,0};
  {
    const unsigned short* Ap = A2 + (size_t)(layer*HCH + hc)*TTC*128 + (size_t)(lane&15)*128;
    #pragma unroll
    for (int ks=0; ks<2; ks++){
      int kb = ks*32 + krow8;
      bf8v bfr = *(const bf8v*)(suh + (size_t)((c*8 + (kb>>3)) ^ swz)*8);
      acc0 = MFMA16(*(const bf8v*)(Ap + 0*16*128 + kb), bfr, acc0);
      acc1 = MFMA16(*(const bf8v*)(Ap + 1*16*128 + kb), bfr, acc1);
      acc2 = MFMA16(*(const bf8v*)(Ap + 2*16*128 + kb), bfr, acc2);
      acc3 = MFMA16(*(const bf8v*)(Ap + 3*16*128 + kb), bfr, acc3);
    }
    #pragma unroll
    for (int ks=2; ks<4; ks++){
      int kb = ks*32 + krow8;
      int w = (kb-64)>>2;
      float4 s0 = *(const float4*)(sE + (size_t)((c*16 + w  ) ^ swz)*4);
      float4 s1 = *(const float4*)(sE + (size_t)((c*16 + w+1) ^ swz)*4);
      bf8v bhv = pack8(s0,s1);
      acc0 = MFMA16(*(const bf8v*)(Ap + 0*16*128 + kb), bhv, acc0);
      acc1 = MFMA16(*(const bf8v*)(Ap + 1*16*128 + kb), bhv, acc1);
      acc2 = MFMA16(*(const bf8v*)(Ap + 2*16*128 + kb), bhv, acc2);
      acc3 = MFMA16(*(const bf8v*)(Ap + 3*16*128 + kb), bhv, acc3);
      float4 r0, r1;
      r0.x = s0.x - bf2f(f2bf(s0.x)); r0.y = s0.y - bf2f(f2bf(s0.y));
      r0.z = s0.z - bf2f(f2bf(s0.z)); r0.w = s0.w - bf2f(f2bf(s0.w));
      r1.x = s1.x - bf2f(f2bf(s1.x)); r1.y = s1.y - bf2f(f2bf(s1.y));
      r1.z = s1.z - bf2f(f2bf(s1.z)); r1.w = s1.w - bf2f(f2bf(s1.w));
      bf8v blv = pack8(r0,r1);
      acc0 = MFMA16(*(const bf8v*)(Ap + 0*16*128 + kb), blv, acc0);
      acc1 = MFMA16(*(const bf8v*)(Ap + 1*16*128 + kb), blv, acc1);
      acc2 = MFMA16(*(const bf8v*)(Ap + 2*16*128 + kb), blv, acc2);
      acc3 = MFMA16(*(const bf8v*)(Ap + 3*16*128 + kb), blv, acc3);
    }
  }
  __syncthreads();   // all sE reads done; reuse as ybuf

  {
    float* ybuf = sE;
    float Dv = Dg[layer*HCH + hc];
    int tq = (lane>>4)*4;
    int sw2 = craw&7;
    #pragma unroll
    for (int m=0;m<4;m++){
      f32x4 av = (m==0)?acc0:((m==1)?acc1:((m==2)?acc2:acc3));
      int base = m*16 + tq;
      int pc_ = (craw*8 + (base>>3)) ^ sw2;
      us4v uv = *(const us4v*)(suh + (size_t)pc_*8 + ((base>>2)&1)*4);
      float4 o4;
      o4.x = gelu_f(av[0] + Dv*bf2f(uv[0]));
      o4.y = gelu_f(av[1] + Dv*bf2f(uv[1]));
      o4.z = gelu_f(av[2] + Dv*bf2f(uv[2]));
      o4.w = gelu_f(av[3] + Dv*bf2f(uv[3]));
      int q4 = craw*16 + (base>>2);
      *(float4*)(ybuf + (size_t)(q4 ^ sw2)*4) = o4;
    }
  }
  __syncthreads();
  unsigned short* ygp = yg + (size_t)bh*LSEQ;
  #pragma unroll
  for (int pass=0; pass<4; pass++){
    int idx = pass*320 + tid;                  // float4 index, < 1280
    if (idx < 1250){
      float4 v = *(const float4*)(sE + (size_t)(idx ^ ((idx>>4)&7))*4);
      us4v o;
      o[0]=f2bf(v.x); o[1]=f2bf(v.y); o[2]=f2bf(v.z); o[3]=f2bf(v.w);
      *(us4v*)(ygp + idx*4) = o;
    }
  }
}

// ---------------- GEMM + GLU + residual + lazy BN + (BN stats) ----------------
// grid 512 = 8 XCD-co-located gt x (b,lg); A in LDS once (global_load_lds);
// B transposed from yg[b][h][l] via reg-staged ds_write_b16 into swizzled LDS,
// 2-slot LDS + 4 reg sets, counted vmcnt (12 steady), lgkmcnt(0) before read-barrier.

static __device__ __forceinline__ void stageA(
    const unsigned short* __restrict__ g, unsigned short* sbuf, int tid)
{
  #pragma unroll
  for (int i=0;i<8;i++){
    int p = i*256 + tid;
    int row = p>>5, kc = p&31;
    int kcl = kc ^ (row&7);
    const unsigned short* ga = g + (size_t)row*HCH + kcl*8;
    __builtin_amdgcn_global_load_lds(
        (const __attribute__((address_space(1))) void*)ga,
        (__attribute__((address_space(3))) void*)(sbuf + p*8),
        16, 0, 0);
  }
}
static __device__ __forceinline__ bf8v ldsF(const unsigned short* sbuf, int row, int k0){
  int byte = (row<<9) + (k0<<1);
  byte ^= ((row&7)<<4);
  return *(const bf8v*)((const char*)sbuf + byte);
}

template<int DO_STATS, int DO_BN>
__global__ __launch_bounds__(256, 2) void k_gemm(
    const unsigned short* __restrict__ Wp, const float* __restrict__ bp,
    const unsigned short* __restrict__ yg, float* __restrict__ hbuf,
    float* __restrict__ bnsum, float* __restrict__ bnsq,
    const float* __restrict__ scale, const float* __restrict__ shift,
    float* __restrict__ dump, int layer)
{
  __shared__ unsigned short As[64*256];      // 32KB
  __shared__ unsigned short Bs[2][32*256];   // 32KB
  int id = blockIdx.x;
  int x = id & 7, s = id >> 3;
  int gt = s & 7;
  int q = x*8 + (s>>3);
  int b = q >> 3, lg = q & 7;
  int l0 = lg*640;

  int tid = threadIdx.x, wid = tid>>6, lane = tid&63;
  int wm = wid>>1, wn = wid&1;
  int colA = lane&15;
  int krow8 = (lane>>4)*8;

  const unsigned short* Wt = Wp + (size_t)layer*G2C*HCH + (size_t)(gt*64)*HCH;
  const unsigned short* Yh = yg + (size_t)(b*HCH + tid)*LSEQ + l0;  // this thread's h row
  stageA(Wt, As, tid);

  float4 bias4[2]; int hc0[2];
  float bsc0[2], bsh0[2], bsc1[2], bsh1[2];
  #pragma unroll
  for (int m=0;m<2;m++){
    int g2r4 = gt*64 + wm*32 + m*16 + (lane>>4)*4;
    bias4[m] = *(const float4*)(bp + layer*G2C + g2r4);
    hc0[m] = g2r4 >> 1;
    if (DO_BN){
      bsc0[m] = scale[hc0[m]];   bsh0[m] = shift[hc0[m]];
      bsc1[m] = scale[hc0[m]+1]; bsh1[m] = shift[hc0[m]+1];
    }
  }
  float sacc[4], qacc[4];
  if (DO_STATS){
    #pragma unroll
    for (int i=0;i<4;i++){ sacc[i]=0.0f; qacc[i]=0.0f; }
  }

  us8v R0[4], R1[4], R2[4], R3[4];
  #define LOADSET(R, tt) { _Pragma("unroll") \
    for (int i_=0;i_<4;i_++) R[i_] = *(const us8v*)(Yh + (size_t)(tt)*32 + i_*8); }
  #define DSWR(R) { _Pragma("unroll") \
    for (int i_=0;i_<4;i_++){ _Pragma("unroll") \
      for (int e_=0;e_<8;e_++){ int row_ = i_*8+e_; \
        int byte_ = row_*512 + ((tid*2) ^ ((row_&7)<<4)); \
        *(unsigned short*)((char*)Bw + byte_) = R[i_][e_]; } } }

  LOADSET(R0, 0); LOADSET(R1, 1);

  const int NT = 20;
  #pragma unroll 4
  for (int t=0; t<NT; t++){
    if (t==0)           asm volatile("s_waitcnt vmcnt(4)"  ::: "memory");
    else if (t < NT-1)  asm volatile("s_waitcnt vmcnt(12)" ::: "memory");
    else                asm volatile("s_waitcnt vmcnt(8)"  ::: "memory");
    __builtin_amdgcn_s_barrier();            // prior readers of slot t&1 done
    unsigned short* Bw = Bs[t&1];
    if ((t&3)==0)      DSWR(R0)
    else if ((t&3)==1) DSWR(R1)
    else if ((t&3)==2) DSWR(R2)
    else               DSWR(R3);
    if (t+2 < NT){
      if (((t+2)&3)==0)      LOADSET(R0, t+2)
      else if (((t+2)&3)==1) LOADSET(R1, t+2)
      else if (((t+2)&3)==2) LOADSET(R2, t+2)
      else                   LOADSET(R3, t+2);
    }
    asm volatile("s_waitcnt lgkmcnt(0)" ::: "memory");
    __builtin_amdgcn_s_barrier();            // B_t visible
    const unsigned short* Bc = Bs[t&1];
    f32x4 acc0 = (f32x4){0,0,0,0}, acc1 = (f32x4){0,0,0,0};
    #pragma unroll
    for (int ks=0; ks<8; ks++){
      int k0 = ks*32 + krow8;
      bf8v fb  = ldsF(Bc, wn*16 + colA, k0);
      bf8v fa0 = ldsF(As, wm*32 + colA, k0);
      bf8v fa1 = ldsF(As, wm*32 + 16 + colA, k0);
      acc0 = MFMA16(fa0, fb, acc0);
      acc1 = MFMA16(fa1, fb, acc1);
    }
    int l = l0 + t*32 + wn*16 + colA;
    bool valid = (l < LSEQ);
    float vmsk = valid ? 1.0f : 0.0f;
    #pragma unroll
    for (int m=0;m<2;m++){
      f32x4 av = m ? acc1 : acc0;
      float a0 = av[0] + bias4[m].x;
      float g0 = av[1] + bias4[m].y;
      float a1 = av[2] + bias4[m].z;
      float g1 = av[3] + bias4[m].w;
      float z0 = a0 * sigm(g0);
      float z1 = a1 * sigm(g1);
      float* pp0 = hbuf + ((size_t)(b*HCH + hc0[m]))*LSEQ + l;
      float* pp1 = pp0 + LSEQ;
      if (!valid){ pp0 = dump + tid; pp1 = dump + 256 + tid; }
      float o0 = pp0[0], o1 = pp1[0];
      if (DO_BN){
        o0 = fmaf(o0, bsc0[m], bsh0[m]);
        o1 = fmaf(o1, bsc1[m], bsh1[m]);
      }
      float r0 = z0 + o0, r1 = z1 + o1;
      pp0[0] = r0; pp1[0] = r1;
      if (DO_STATS){
        float s0 = r0*vmsk, s1 = r1*vmsk;
        sacc[m*2+0] += s0; qacc[m*2+0] += s0*s0;
        sacc[m*2+1] += s1; qacc[m*2+1] += s1*s1;
      }
    }
  }
  #undef LOADSET
  #undef DSWR

  if (DO_STATS){
    #pragma unroll
    for (int m=0;m<2;m++){
      #pragma unroll
      for (int zr=0; zr<2; zr++){
        float sv = sacc[m*2+zr], qv = qacc[m*2+zr];
        sv += __shfl_xor(sv,1); qv += __shfl_xor(qv,1);
        sv += __shfl_xor(sv,2); qv += __shfl_xor(qv,2);
        sv += __shfl_xor(sv,4); qv += __shfl_xor(qv,4);
        sv += __shfl_xor(sv,8); qv += __shfl_xor(qv,8);
        if ((lane&15)==0){
          atomicAdd(&bnsum[hc0[m]+zr], sv);
          atomicAdd(&bnsq[hc0[m]+zr], qv);
        }
      }
    }
  }
}

// ---------------- batchnorm finalize ----------------

__global__ void k_bnfin(const float* __restrict__ bnsum, const float* __restrict__ bnsq,
    const float* __restrict__ gam, const float* __restrict__ bet,
    float* __restrict__ scale, float* __restrict__ shift, int bnidx)
{
  int hc = threadIdx.x;
  const float inv = 1.0f/40000.0f;
  float mean = bnsum[hc]*inv;
  float var = bnsq[hc]*inv - mean*mean;
  float sc = gam[bnidx*HCH + hc] * rsqrtf(var + 1e-5f);
  scale[hc] = sc;
  shift[hc] = bet[bnidx*HCH + hc] - mean*sc;
}

// ---------------- final transpose h[b][h][l] -> out[b][l][h] ----------------

__global__ __launch_bounds__(256) void k_outT(const float* __restrict__ hbuf,
    float* __restrict__ out)
{
  __shared__ float tile[64][65];
  int b = blockIdx.z, h0 = blockIdx.y*64, l0 = blockIdx.x*64;
  int tid = threadIdx.x;
  #pragma unroll
  for (int i=0;i<4;i++){
    int lidx = tid + i*256;
    int row = lidx>>4, c4 = (lidx&15)*4;
    float4 v = {0,0,0,0};
    if (l0 + c4 < LSEQ)
      v = *(const float4*)(hbuf + (size_t)(b*HCH + h0 + row)*LSEQ + l0 + c4);
    tile[row][c4+0]=v.x; tile[row][c4+1]=v.y; tile[row][c4+2]=v.z; tile[row][c4+3]=v.w;
  }
  __syncthreads();
  #pragma unroll
  for (int i=0;i<4;i++){
    int widx = tid + i*256;
    int r = widx>>4, h4 = (widx&15)*4;
    int l = l0 + r;
    if (l < LSEQ){
      float4 o = { tile[h4+0][r], tile[h4+1][r], tile[h4+2][r], tile[h4+3][r] };
      *(float4*)(out + ((size_t)(b*LSEQ) + l)*HCH + h0 + h4) = o;
    }
  }
}

// ---------------- host ----------------

extern "C" void kernel_launch(void* const* d_in, const int* in_sizes, int n_in,
                              void* d_out, int out_size, void* d_ws, size_t ws_size,
                              hipStream_t stream)
{
  (void)in_sizes; (void)n_in; (void)out_size; (void)ws_size;
  const float* x      = (const float*)d_in[0];
  const float* pre_w  = (const float*)d_in[1];
  const float* pre_b  = (const float*)d_in[2];
  const float* log_dt = (const float*)d_in[3];
  const float* C_re   = (const float*)d_in[4];
  const float* C_im   = (const float*)d_in[5];
  const float* lAr    = (const float*)d_in[6];
  const float* A_im   = (const float*)d_in[7];
  const float* Dg     = (const float*)d_in[8];
  const float* out_w  = (const float*)d_in[9];
  const float* out_b  = (const float*)d_in[10];
  const float* gam    = (const float*)d_in[11];
  const float* bet    = (const float*)d_in[12];
  float* out = (float*)d_out;

  char* ws = (char*)d_ws;
  size_t off = 0;
  auto alloc = [&](size_t bytes)->char*{
    char* p = ws + off;
    off += (bytes + 255) & ~(size_t)255;
    return p;
  };
  float*          hbuf  = (float*)         alloc((size_t)(NB*HCH*LSEQ + 8192)*4);
  unsigned short* yg    = (unsigned short*)alloc((size_t)(NB*HCH*LSEQ + 8192)*2);
  float*          p_ar  = (float*)         alloc((size_t)NLAY*HCH*N2C*4);
  float*          p_ai  = (float*)         alloc((size_t)NLAY*HCH*N2C*4);
  float*          p_cer = (float*)         alloc((size_t)NLAY*HCH*N2C*4);
  float*          p_cei = (float*)         alloc((size_t)NLAY*HCH*N2C*4);
  float*          p_wtr = (float*)         alloc((size_t)NLAY*HCH*N2C*4);
  float*          p_wti = (float*)         alloc((size_t)NLAY*HCH*N2C*4);
  float*          kk    = (float*)         alloc((size_t)NLAY*HCH*TTC*4);
  unsigned short* A2b   = (unsigned short*)alloc((size_t)NLAY*HCH*TTC*128*2);
  unsigned short* Vmb   = (unsigned short*)alloc((size_t)NLAY*HCH*TTC*TTC*2);
  unsigned short* Wpb   = (unsigned short*)alloc((size_t)NLAY*G2C*HCH*2);
  float*          bp    = (float*)         alloc((size_t)NLAY*G2C*4);
  float*          bnst  = (float*)         alloc((size_t)4*HCH*4);
  float* bnsum = bnst, *bnsq = bnst + HCH, *bnscale = bnst + 2*HCH, *bnshift = bnst + 3*HCH;
  float* dump = hbuf + (size_t)NB*HCH*LSEQ;

  kp_params<<<(NLAY*HCH*N2C)/256, 256, 0, stream>>>(log_dt, lAr, A_im, C_re, C_im,
      p_ar, p_ai, p_cer, p_cei, p_wtr, p_wti);
  kp_kk<<<(NLAY*HCH*TTC)/256, 256, 0, stream>>>(p_ar, p_ai, p_cer, p_cei, kk);
  kp_A2<<<(NLAY*HCH*TTC*128)/256, 256, 0, stream>>>(p_ar, p_ai, p_cer, p_cei, kk, A2b);
  kp_Vm<<<(NLAY*HCH*TTC*TTC)/256, 256, 0, stream>>>(p_ar, p_ai, Vmb);
  kp_Wp<<<(NLAY*G2C*HCH)/256, 256, 0, stream>>>(out_w, out_b, Wpb, bp);

  k_preproj<<<dim3(20, HCH, NB), 256, 0, stream>>>(x, pre_w, pre_b, hbuf);

  for (int layer=0; layer<NLAY; layer++){
    if (layer & 1)
      k_row<1><<<NB*HCH, 320, 0, stream>>>(Vmb, A2b, p_wtr, p_wti, Dg, hbuf,
                                           bnscale, bnshift, yg, layer);
    else
      k_row<0><<<NB*HCH, 320, 0, stream>>>(Vmb, A2b, p_wtr, p_wti, Dg, hbuf,
                                           bnscale, bnshift, yg, layer);
    if ((layer & 1) == 0){
      hipMemsetAsync(bnsum, 0, 2*HCH*sizeof(float), stream);
      k_gemm<1,0><<<512, 256, 0, stream>>>(Wpb, bp, yg, hbuf, bnsum, bnsq,
                                           bnscale, bnshift, dump, layer);
      k_bnfin<<<1, HCH, 0, stream>>>(bnsum, bnsq, gam, bet, bnscale, bnshift, layer/2);
    } else {
      k_gemm<0,1><<<512, 256, 0, stream>>>(Wpb, bp, yg, hbuf, bnsum, bnsq,
                                           bnscale, bnshift, dump, layer);
    }
  }
  k_outT<<<dim3(79, HCH/64, NB), 256, 0, stream>>>(hbuf, out);
}